// Round 16
// baseline (169.067 us; speedup 1.0000x reference)
//
#include <hip/hip_runtime.h>
#include <math.h>

#define NI 128
#define NC 256
#define NR 36
#define NW 48
#define ND 256

#define PIB 264      // sIb pitch (bf16): 528 B rows -> 2-way banks on b128 reads: free
#define PG  72       // sG pitch: 144 B rows, 2-way banks; cols 36..71 stay zero (k-pad)
#define PSP 52       // sP pitch: quad write-offsets {0,8,16,24} banks -> conflict-free writes;
                     // read spans 2-way overlap (free). 2x16-row buffers/wave (W/R pipeline).

// lambda_softmax(9) * log2(e); lambda_lse(6) * log2(e); ln2/6 (LSE un-log2)
#define SOFT_SCALE 12.984255368000671f
#define LSE_SCALE   8.656170245333781f
#define LN2_OVER_6  0.11552453009332422f

typedef __bf16 bf16;
typedef __bf16 bf16x8 __attribute__((ext_vector_type(8)));
typedef __bf16 bf16x4 __attribute__((ext_vector_type(4)));
typedef float  f32x4  __attribute__((ext_vector_type(4)));

// LDS carve (bytes) — 37632 total (R8 carve, proven best)
#define OFF_IB    0        // 36*264*2 = 19008
#define OFF_G     19008    // 36*72*2  = 5184  -> 24192
#define OFF_P     24192    // 4 waves x 2 buffers x 16*52*2 = 13312 -> 37504
#define OFF_GUARD 37504    // 128 B zero tail (row-15 pa1 overread of last wave's bufB)
#define SMEM_TOTAL 37632

#define MFMA16(A,B,C) __builtin_amdgcn_mfma_f32_16x16x32_bf16(A, B, C, 0, 0, 0)

__device__ __forceinline__ float dpp_add16(float v) {
    int x = __builtin_bit_cast(int, v);
    v += __builtin_bit_cast(float, __builtin_amdgcn_update_dpp(0, x, 0xB1, 0xF, 0xF, true));
    x = __builtin_bit_cast(int, v);
    v += __builtin_bit_cast(float, __builtin_amdgcn_update_dpp(0, x, 0x4E, 0xF, 0xF, true));
    x = __builtin_bit_cast(int, v);
    v += __builtin_bit_cast(float, __builtin_amdgcn_update_dpp(0, x, 0x141, 0xF, 0xF, true));
    x = __builtin_bit_cast(int, v);
    v += __builtin_bit_cast(float, __builtin_amdgcn_update_dpp(0, x, 0x140, 0xF, 0xF, true));
    return v;
}

// Full-wave sum via DPP (VALU pipe, no LDS). Caller's per-lane values are identical
// within each 16-lane row, so the 64-lane total = 16x the 4-row target; caller scales
// by exactly 1/16. Verified numerically in R14/R15 (absmax 0.0039 pass).
__device__ __forceinline__ float wave_sum_row3(float v) {
    v = dpp_add16(v);
    int x = __builtin_bit_cast(int, v);
    v += __builtin_bit_cast(float, __builtin_amdgcn_update_dpp(0, x, 0x142, 0xF, 0xF, true));
    x = __builtin_bit_cast(int, v);
    v += __builtin_bit_cast(float, __builtin_amdgcn_update_dpp(0, x, 0x143, 0xF, 0xF, true));
    return v;
}

// leaky_relu(0.1) as 2 VALU ops: 0.55t + 0.45|t|
__device__ __forceinline__ float lrelu(float t) {
    return __builtin_fmaf(0.55f, t, 0.45f * __builtin_fabsf(t));
}

// fast log: v_log_f32 gives log2(x); sim = log2(esum) * ln2/6 == ln(esum)/6
__device__ __forceinline__ float lse_out(float esum) {
#if __has_builtin(__builtin_amdgcn_logf)
    return __builtin_amdgcn_logf(esum) * LN2_OVER_6;
#else
    return logf(esum) * (1.0f / 6.0f);
#endif
}

// ---- prep: captions fp32 -> bf16 cache + per-caption-row LSE_SCALE/||row|| ----
__global__ __launch_bounds__(256)
void prep_kernel(const float* __restrict__ captions, bf16* __restrict__ capb,
                 float* __restrict__ w1g)
{
    const int c = blockIdx.x >> 2, q = blockIdx.x & 3;
    const int wave = threadIdx.x >> 6, lane = threadIdx.x & 63;
    #pragma unroll
    for (int j = 0; j < 3; ++j) {
        int w = q * 12 + wave * 3 + j;
        size_t off = ((size_t)c * NW + w) * ND + lane * 4;
        float4 v = *(const float4*)(captions + off);
        bf16x4 h = { (bf16)v.x, (bf16)v.y, (bf16)v.z, (bf16)v.w };
        *(bf16x4*)(capb + off) = h;
        float s = v.x*v.x + v.y*v.y + v.z*v.z + v.w*v.w;
        s += __shfl_xor(s, 1);  s += __shfl_xor(s, 2);  s += __shfl_xor(s, 4);
        s += __shfl_xor(s, 8);  s += __shfl_xor(s, 16); s += __shfl_xor(s, 32);
        if (lane == 0) w1g[c * NW + w] = LSE_SCALE / sqrtf(s);
    }
}

__device__ __forceinline__ bf16x8 ld_cvt_f32(const float* p, float& ss) {
    float4 lo = *(const float4*)p;
    float4 hi = *(const float4*)(p + 4);
    ss += lo.x*lo.x + lo.y*lo.y + lo.z*lo.z + lo.w*lo.w
        + hi.x*hi.x + hi.y*hi.y + hi.z*hi.z + hi.w*hi.w;
    bf16x8 r = { (bf16)lo.x, (bf16)lo.y, (bf16)lo.z, (bf16)lo.w,
                 (bf16)hi.x, (bf16)hi.y, (bf16)hi.z, (bf16)hi.w };
    return r;
}

// W-stage: softmax weights for one mt-tile -> IN-PLACE into acc[MT] + write to sP buffer.
#define STAGE_W(MT, BUF, W12) do {                                                      \
    _Pragma("unroll")                                                                   \
    for (int p = 0; p < 4; ++p) {                                                       \
        float a0v = acc[MT][0][p], a1v = acc[MT][1][p], a2v = acc[MT][2][p];            \
        float e0 = exp2f(__builtin_fmaf(c1[0], a0v, c2[0] * __builtin_fabsf(a0v)));     \
        float e1 = exp2f(__builtin_fmaf(c1[1], a1v, c2[1] * __builtin_fabsf(a1v)));     \
        float e2 = (l15 >= 12)                                                          \
            ? exp2f(__builtin_fmaf(c1[2], a2v, c2[2] * __builtin_fabsf(a2v)))           \
            : 0.f;                                        /* r=32..35 only */           \
        W12[p] = e0 * a0v + e1 * a1v + e2 * a2v;                                        \
        acc[MT][0][p] = e0; acc[MT][1][p] = e1; acc[MT][2][p] = e2;   /* in-place */    \
        int row = quad * 4 + p;                                                         \
        (BUF)[row * PSP + l15]      = (bf16)e0;                                         \
        (BUF)[row * PSP + 16 + l15] = (bf16)e1;                                         \
        if (l15 >= 12) (BUF)[row * PSP + rb2 + l15] = (bf16)e2;   /* cols 32..35 */     \
    }                                                                                   \
} while (0)

// R-stage: PV MFMA via Gram + epilogue. Reads BUF written >=1 full stage earlier.
// setprio(1) around the MFMA cluster (R10, +1.5-2%). w1g float4 loaded per-mt INSIDE
// the stage (R14's hoist held 12 regs live across the epilogue -> 7.4 MB spill; reverted).
#define STAGE_R(MT, BUF, W12) do {                                                      \
    const bf16* ap = (BUF) + l15 * PSP;                                                 \
    bf16x8 pa0 = *(const bf16x8*)(ap + quad * 8);                                       \
    bf16x8 pa1 = *(const bf16x8*)(ap + 32 + quad * 8);  /* cols>=36: finite x G-zeros */\
    f32x4 pg0 = {0,0,0,0}, pg1 = {0,0,0,0}, pg2 = {0,0,0,0};                            \
    {                                                                                   \
        bf16x8 t0 = *(const bf16x8*)&sG[(l15) * PG + quad * 8];                         \
        bf16x8 t1 = *(const bf16x8*)&sG[(l15) * PG + 32 + quad * 8];                    \
        bf16x8 t2 = *(const bf16x8*)&sG[(16 + l15) * PG + quad * 8];                    \
        bf16x8 t3 = *(const bf16x8*)&sG[(16 + l15) * PG + 32 + quad * 8];               \
        bf16x8 t4 = *(const bf16x8*)&sG[(rb2 + l15) * PG + quad * 8];                   \
        bf16x8 t5 = *(const bf16x8*)&sG[(rb2 + l15) * PG + 32 + quad * 8];              \
        __builtin_amdgcn_s_setprio(1);                                                  \
        pg0 = MFMA16(pa0, t0, pg0); pg0 = MFMA16(pa1, t1, pg0);                         \
        pg1 = MFMA16(pa0, t2, pg1); pg1 = MFMA16(pa1, t3, pg1);                         \
        pg2 = MFMA16(pa0, t4, pg2); pg2 = MFMA16(pa1, t5, pg2);                         \
        __builtin_amdgcn_s_setprio(0);                                                  \
    }                                                                                   \
    float4 wq = {0.f, 0.f, 0.f, 0.f};                                                   \
    if constexpr (USE_WS)                                                               \
        wq = *(const float4*)&w1g[(size_t)c * NW + (MT) * 16 + quad * 4];               \
    _Pragma("unroll")                                                                   \
    for (int p = 0; p < 4; ++p) {                                                       \
        float s2 = pg0[p] * acc[MT][0][p] + pg1[p] * acc[MT][1][p]                      \
                 + pg2[p] * acc[MT][2][p];                    /* acc holds e (f32) */   \
        s2 = dpp_add16(s2);                                                             \
        float w12 = dpp_add16(W12[p]);                                                  \
        float wf = USE_WS ? ((const float*)&wq)[p] : w1f[MT][p];                        \
        esum += exp2f(w12 * __frsqrt_rn(fmaxf(s2, 1e-16f)) * wf);                       \
    }                                                                                   \
} while (0)

// Ledger: R8 W/R pipeline 122->115.6; R10 setprio ->113.5; R15 DPP join+v_log = null
// (kept, clean canaries). R9/R14 lesson: any edit adding >=8 LIVE registers spills.
// R16: next-caption ks=0 A-fragment prefetch placed where acc[0] dies (STAGE_R(0) end):
// 12 regs die, 12 born -> peak pressure unchanged BY CONSTRUCTION. Hides the QK
// lead-in (3 dependent L2 loads, ~200-400 cy) behind STAGE_W(2)/R(1)/R(2).
// Spill canary: WRITE_SIZE must stay ~135 KB; VGPR must stay 60.
template<bool USE_WS>
__global__ __attribute__((amdgpu_flat_work_group_size(256, 256), amdgpu_waves_per_eu(4, 8)))
void scan_main(const float* __restrict__ images,
               const float* __restrict__ captions,
               const bf16* __restrict__ capb,
               const float* __restrict__ w1g,
               float* __restrict__ out)
{
    __shared__ __align__(16) unsigned char smem[SMEM_TOTAL];
    bf16* sIb = (bf16*)(smem + OFF_IB);   // [r][d] image, 36 real rows only
    bf16* sG  = (bf16*)(smem + OFF_G);    // [r'][r] Gram, 36 rows x 72 cols (36..71 zero)

    const int tid  = threadIdx.x;
    const int wave = tid >> 6;
    const int lane = tid & 63;
    const int quad = lane >> 4;
    const int l15  = lane & 15;
    const int i    = blockIdx.x >> 4;
    const int c0   = (blockIdx.x & 15) * 16;  // chunk -> (chunk%8) XCD-affine captions

    bf16* bufA = (bf16*)(smem + OFF_P) + wave * (32 * PSP);   // two 16-row buffers
    bf16* bufB = bufA + 16 * PSP;

    const int rb2 = 20;   // r-tile bases {0,16,20}; tile 2 overlaps tile 1 on r=20..31

    // ---- init: stage image bf16, zero sG and sP+guard ----
    const float* gI = images + (size_t)i * NR * ND;
    #pragma unroll
    for (int k = 0; k < 9; ++k) {
        int t = tid + k * 256;               // 2304 float4
        int e = t * 4, r = e >> 8, d = e & 255;
        float4 v = *(const float4*)(gI + e);
        bf16x4 h = { (bf16)v.x, (bf16)v.y, (bf16)v.z, (bf16)v.w };
        *(bf16x4*)&sIb[r * PIB + d] = h;
    }
    {
        uint32_t* pG = (uint32_t*)sG;        // 1296 dwords
        #pragma unroll
        for (int k = 0; k < 6; ++k) { int x = tid + k * 256; if (x < 1296) pG[x] = 0u; }
        uint32_t* pP = (uint32_t*)(smem + OFF_P);   // sP buffers + guard: 3360 dwords
        #pragma unroll
        for (int k = 0; k < 14; ++k) { int x = tid + k * 256; if (x < 3360) pP[x] = 0u; }
        // cols 36..51 of each sP row are never written after this -> stay zero (k-pad safety)
    }
    __syncthreads();   // B0

    // ---- once: Gram G = I*I^T over overlapped m-tiles {0,16,20} (waves 0-2) ----
    if (wave < 3) {
        const int mb = (wave == 2) ? rb2 : wave * 16;
        f32x4 g0 = {0,0,0,0}, g1 = {0,0,0,0}, g2 = {0,0,0,0};
        #pragma unroll
        for (int ks = 0; ks < 8; ++ks) {
            bf16x8 a  = *(const bf16x8*)&sIb[(mb + l15)  * PIB + ks * 32 + quad * 8];
            bf16x8 b0 = *(const bf16x8*)&sIb[(l15)       * PIB + ks * 32 + quad * 8];
            bf16x8 b1 = *(const bf16x8*)&sIb[(16 + l15)  * PIB + ks * 32 + quad * 8];
            bf16x8 b2 = *(const bf16x8*)&sIb[(rb2 + l15) * PIB + ks * 32 + quad * 8];
            g0 = MFMA16(a, b0, g0); g1 = MFMA16(a, b1, g1); g2 = MFMA16(a, b2, g2);
        }
        // duplicate writes in overlap regions carry identical values (benign)
        #pragma unroll
        for (int p = 0; p < 4; ++p) {
            int m = mb + quad * 4 + p;
            sG[m * PG + l15]       = (bf16)g0[p];
            sG[m * PG + 16 + l15]  = (bf16)g1[p];
            sG[m * PG + rb2 + l15] = (bf16)g2[p];
        }
    }
    __syncthreads();   // B1: sG published. No further barriers.

    // ---- per-wave: 4 captions, everything in-wave ----
    const size_t cstep = (size_t)NW * ND;
    const bf16* abit = USE_WS
        ? capb + ((size_t)(c0 + wave * 4) * NW + l15) * ND + quad * 8 : nullptr;
    bf16x8 pf0, pf1, pf2;                    // next-caption ks=0 A-fragments (12 VGPR)
    if constexpr (USE_WS) {
        pf0 = *(const bf16x8*)(abit);
        pf1 = *(const bf16x8*)(abit + 16 * ND);
        pf2 = *(const bf16x8*)(abit + 32 * ND);
    }

    for (int it = 0; it < 4; ++it) {
        const int c = c0 + wave * 4 + it;

        // ---- phase 1: raw logits attnT[w][r] = C_c . I^T ----
        f32x4 acc[3][3] = {};
        float ssc[3] = {0.f, 0.f, 0.f};
        float w1f[3][4] = {};                 // !USE_WS only (fallback path)
        const bf16*  ab   = abit;
        const float* ab32 = USE_WS ? nullptr : captions + ((size_t)c * NW + l15) * ND + quad * 8;
        __builtin_amdgcn_s_setprio(1);        // MFMA-dense phase: bias CU scheduler
        #pragma unroll
        for (int ks = 0; ks < 8; ++ks) {
            bf16x8 a0, a1, a2;
            if (USE_WS) {
                if (ks == 0) {                // prefetched last epilogue (or prologue)
                    a0 = pf0; a1 = pf1; a2 = pf2;
                } else {
                    a0 = *(const bf16x8*)(ab + ks * 32);
                    a1 = *(const bf16x8*)(ab + 16 * ND + ks * 32);
                    a2 = *(const bf16x8*)(ab + 32 * ND + ks * 32);
                }
            } else {
                a0 = ld_cvt_f32(ab32 + ks * 32, ssc[0]);
                a1 = ld_cvt_f32(ab32 + 16 * ND + ks * 32, ssc[1]);
                a2 = ld_cvt_f32(ab32 + 32 * ND + ks * 32, ssc[2]);
            }
            bf16x8 b0 = *(const bf16x8*)&sIb[(l15)       * PIB + ks * 32 + quad * 8];
            bf16x8 b1 = *(const bf16x8*)&sIb[(16 + l15)  * PIB + ks * 32 + quad * 8];
            bf16x8 b2 = *(const bf16x8*)&sIb[(rb2 + l15) * PIB + ks * 32 + quad * 8];
            acc[0][0] = MFMA16(a0, b0, acc[0][0]);
            acc[1][0] = MFMA16(a1, b0, acc[1][0]);
            acc[2][0] = MFMA16(a2, b0, acc[2][0]);
            acc[0][1] = MFMA16(a0, b1, acc[0][1]);
            acc[1][1] = MFMA16(a1, b1, acc[1][1]);
            acc[2][1] = MFMA16(a2, b1, acc[2][1]);
            acc[0][2] = MFMA16(a0, b2, acc[0][2]);
            acc[1][2] = MFMA16(a1, b2, acc[1][2]);
            acc[2][2] = MFMA16(a2, b2, acc[2][2]);
        }
        __builtin_amdgcn_s_setprio(0);
        if (!USE_WS) {
            #pragma unroll
            for (int mt = 0; mt < 3; ++mt) {
                float s = ssc[mt];
                s += __shfl_xor(s, 16); s += __shfl_xor(s, 32);
                ssc[mt] = LSE_SCALE * __frsqrt_rn(fmaxf(s, 1e-16f));   // = LSE/w1
            }
            #pragma unroll
            for (int mt = 0; mt < 3; ++mt)
                #pragma unroll
                for (int p = 0; p < 4; ++p)
                    w1f[mt][p] = __shfl(ssc[mt], (lane & 48) + quad * 4 + p);
        }

        // ---- l2norm over w; nt=2 valid at l15>=12 (r=32..35) ----
        // fold 9*log2e*inv into the exp2 argument: exp2(c1*a + c2*|a|)
        float c1[3], c2[3];
        #pragma unroll
        for (int nt = 0; nt < 3; ++nt) {
            float s = 0.f;
            #pragma unroll
            for (int mt = 0; mt < 3; ++mt)
                #pragma unroll
                for (int p = 0; p < 4; ++p) { float t = lrelu(acc[mt][nt][p]); s += t * t; }
            s += __shfl_xor(s, 16); s += __shfl_xor(s, 32);       // sum over w-quads
            float inv = SOFT_SCALE * __frsqrt_rn(fmaxf(s, 1e-12f));
            c1[nt] = 0.55f * inv;
            c2[nt] = 0.45f * inv;
        }

        // ---- W/R pipeline over 2 buffers: every write->read RAW spans a full stage ----
        float esum = 0.f;
        float w12a[4], w12b[4], w12c[4];
        STAGE_W(0, bufA, w12a);
        STAGE_W(1, bufB, w12b);
        STAGE_R(0, bufA, w12a);       // bufA written 1 stage ago; W1's exps in the shadow

        // prefetch next caption's ks=0 fragments HERE: acc[0] just died (-12 regs),
        // pf* born (+12) -> net-zero pressure; ~700 cy ahead of next QK use
        if constexpr (USE_WS) {
            if (it < 3) {
                const bf16* abn = abit + cstep;
                pf0 = *(const bf16x8*)(abn);
                pf1 = *(const bf16x8*)(abn + 16 * ND);
                pf2 = *(const bf16x8*)(abn + 32 * ND);
            }
        }

        STAGE_W(2, bufA, w12c);       // bufA free (R0's reads precede in-wave DS order)
        STAGE_R(1, bufB, w12b);
        STAGE_R(2, bufA, w12c);

        // final join on the VALU pipe (DPP); 64-lane sum = 16x the 4-row target
        // (per-lane esum identical within each row) -> exact 1/16 scale before log
        esum = wave_sum_row3(esum);
        if (lane == 63) out[(size_t)i * NC + c] = lse_out(esum * 0.0625f);

        if constexpr (USE_WS) abit += cstep;
    }
}

extern "C" void kernel_launch(void* const* d_in, const int* in_sizes, int n_in,
                              void* d_out, int out_size, void* d_ws, size_t ws_size,
                              hipStream_t stream) {
    const float* images   = (const float*)d_in[0];   // (128, 36, 256) fp32
    const float* captions = (const float*)d_in[1];   // (256, 48, 256) fp32
    float* out = (float*)d_out;                      // (128, 256) fp32

    const size_t need_w1  = (size_t)NC * NW * sizeof(float);   // 49152
    const size_t need_cap = (size_t)NC * NW * ND * 2;          // 6291456
    bool use_ws = ws_size >= need_w1 + need_cap;

    dim3 grid(2048), block(256);   // R2/R8 launch geometry (proven best)
    if (use_ws) {
        float* w1g = (float*)d_ws;
        bf16*  capb = (bf16*)((char*)d_ws + need_w1);
        hipLaunchKernelGGL(prep_kernel, dim3(1024), dim3(256), 0, stream, captions, capb, w1g);
        hipLaunchKernelGGL((scan_main<true>), grid, block, 0, stream, images, captions, capb, w1g, out);
    } else {
        hipLaunchKernelGGL((scan_main<false>), grid, block, 0, stream, images, captions,
                           (const bf16*)nullptr, (const float*)nullptr, out);
    }
}

// Round 17
// 163.848 us; speedup vs baseline: 1.0319x; 1.0319x over previous
//
#include <hip/hip_runtime.h>
#include <math.h>

#define NI 128
#define NC 256
#define NR 36
#define NW 48
#define ND 256

#define PIB 264      // sIb pitch (bf16): 528 B rows -> 2-way banks on b128 reads: free
#define PG  72       // sG pitch: 144 B rows, 2-way banks; cols 36..71 stay zero (k-pad)
#define PSP 52       // sP pitch: quad write-offsets {0,8,16,24} banks -> conflict-free writes;
                     // read spans 2-way overlap (free). 2x16-row buffers/wave (W/R pipeline).

// lambda_softmax(9) * log2(e); lambda_lse(6) * log2(e); ln2/6 (LSE un-log2)
#define SOFT_SCALE 12.984255368000671f
#define LSE_SCALE   8.656170245333781f
#define LN2_OVER_6  0.11552453009332422f

typedef __bf16 bf16;
typedef __bf16 bf16x8 __attribute__((ext_vector_type(8)));
typedef __bf16 bf16x4 __attribute__((ext_vector_type(4)));
typedef float  f32x4  __attribute__((ext_vector_type(4)));

// LDS carve (bytes) — 37632 total (R8 carve, proven best)
#define OFF_IB    0        // 36*264*2 = 19008
#define OFF_G     19008    // 36*72*2  = 5184  -> 24192
#define OFF_P     24192    // 4 waves x 2 buffers x 16*52*2 = 13312 -> 37504
#define OFF_GUARD 37504    // 128 B zero tail (row-15 pa1 overread of last wave's bufB)
#define SMEM_TOTAL 37632

#define MFMA16(A,B,C) __builtin_amdgcn_mfma_f32_16x16x32_bf16(A, B, C, 0, 0, 0)

__device__ __forceinline__ float dpp_add16(float v) {
    int x = __builtin_bit_cast(int, v);
    v += __builtin_bit_cast(float, __builtin_amdgcn_update_dpp(0, x, 0xB1, 0xF, 0xF, true));
    x = __builtin_bit_cast(int, v);
    v += __builtin_bit_cast(float, __builtin_amdgcn_update_dpp(0, x, 0x4E, 0xF, 0xF, true));
    x = __builtin_bit_cast(int, v);
    v += __builtin_bit_cast(float, __builtin_amdgcn_update_dpp(0, x, 0x141, 0xF, 0xF, true));
    x = __builtin_bit_cast(int, v);
    v += __builtin_bit_cast(float, __builtin_amdgcn_update_dpp(0, x, 0x140, 0xF, 0xF, true));
    return v;
}

// Full-wave sum via DPP (VALU pipe, no LDS). Caller's per-lane values are identical
// within each 16-lane row, so the 64-lane total = 16x the 4-row target; caller scales
// by exactly 1/16. Verified numerically in R14/R15 (absmax 0.0039 pass).
__device__ __forceinline__ float wave_sum_row3(float v) {
    v = dpp_add16(v);
    int x = __builtin_bit_cast(int, v);
    v += __builtin_bit_cast(float, __builtin_amdgcn_update_dpp(0, x, 0x142, 0xF, 0xF, true));
    x = __builtin_bit_cast(int, v);
    v += __builtin_bit_cast(float, __builtin_amdgcn_update_dpp(0, x, 0x143, 0xF, 0xF, true));
    return v;
}

// leaky_relu(0.1) as 2 VALU ops: 0.55t + 0.45|t|
__device__ __forceinline__ float lrelu(float t) {
    return __builtin_fmaf(0.55f, t, 0.45f * __builtin_fabsf(t));
}

// fast log: v_log_f32 gives log2(x); sim = log2(esum) * ln2/6 == ln(esum)/6
__device__ __forceinline__ float lse_out(float esum) {
#if __has_builtin(__builtin_amdgcn_logf)
    return __builtin_amdgcn_logf(esum) * LN2_OVER_6;
#else
    return logf(esum) * (1.0f / 6.0f);
#endif
}

// ---- prep: captions fp32 -> bf16 cache + per-caption-row LSE_SCALE/||row|| ----
__global__ __launch_bounds__(256)
void prep_kernel(const float* __restrict__ captions, bf16* __restrict__ capb,
                 float* __restrict__ w1g)
{
    const int c = blockIdx.x >> 2, q = blockIdx.x & 3;
    const int wave = threadIdx.x >> 6, lane = threadIdx.x & 63;
    #pragma unroll
    for (int j = 0; j < 3; ++j) {
        int w = q * 12 + wave * 3 + j;
        size_t off = ((size_t)c * NW + w) * ND + lane * 4;
        float4 v = *(const float4*)(captions + off);
        bf16x4 h = { (bf16)v.x, (bf16)v.y, (bf16)v.z, (bf16)v.w };
        *(bf16x4*)(capb + off) = h;
        float s = v.x*v.x + v.y*v.y + v.z*v.z + v.w*v.w;
        s += __shfl_xor(s, 1);  s += __shfl_xor(s, 2);  s += __shfl_xor(s, 4);
        s += __shfl_xor(s, 8);  s += __shfl_xor(s, 16); s += __shfl_xor(s, 32);
        if (lane == 0) w1g[c * NW + w] = LSE_SCALE / sqrtf(s);
    }
}

__device__ __forceinline__ bf16x8 ld_cvt_f32(const float* p, float& ss) {
    float4 lo = *(const float4*)p;
    float4 hi = *(const float4*)(p + 4);
    ss += lo.x*lo.x + lo.y*lo.y + lo.z*lo.z + lo.w*lo.w
        + hi.x*hi.x + hi.y*hi.y + hi.z*hi.z + hi.w*hi.w;
    bf16x8 r = { (bf16)lo.x, (bf16)lo.y, (bf16)lo.z, (bf16)lo.w,
                 (bf16)hi.x, (bf16)hi.y, (bf16)hi.z, (bf16)hi.w };
    return r;
}

// W-stage: softmax weights for one mt-tile -> IN-PLACE into acc[MT] + write to sP buffer.
#define STAGE_W(MT, BUF, W12) do {                                                      \
    _Pragma("unroll")                                                                   \
    for (int p = 0; p < 4; ++p) {                                                       \
        float a0v = acc[MT][0][p], a1v = acc[MT][1][p], a2v = acc[MT][2][p];            \
        float e0 = exp2f(__builtin_fmaf(c1[0], a0v, c2[0] * __builtin_fabsf(a0v)));     \
        float e1 = exp2f(__builtin_fmaf(c1[1], a1v, c2[1] * __builtin_fabsf(a1v)));     \
        float e2 = (l15 >= 12)                                                          \
            ? exp2f(__builtin_fmaf(c1[2], a2v, c2[2] * __builtin_fabsf(a2v)))           \
            : 0.f;                                        /* r=32..35 only */           \
        W12[p] = e0 * a0v + e1 * a1v + e2 * a2v;                                        \
        acc[MT][0][p] = e0; acc[MT][1][p] = e1; acc[MT][2][p] = e2;   /* in-place */    \
        int row = quad * 4 + p;                                                         \
        (BUF)[row * PSP + l15]      = (bf16)e0;                                         \
        (BUF)[row * PSP + 16 + l15] = (bf16)e1;                                         \
        if (l15 >= 12) (BUF)[row * PSP + rb2 + l15] = (bf16)e2;   /* cols 32..35 */     \
    }                                                                                   \
} while (0)

// R-stage: PV MFMA via Gram + epilogue. Reads BUF written >=1 full stage earlier.
// setprio(1) around the MFMA cluster (R10, +1.5-2%). w1g float4 loaded per-mt INSIDE
// the stage (R14's hoist held 12 regs live across the epilogue -> 7.4 MB spill; reverted).
#define STAGE_R(MT, BUF, W12) do {                                                      \
    const bf16* ap = (BUF) + l15 * PSP;                                                 \
    bf16x8 pa0 = *(const bf16x8*)(ap + quad * 8);                                       \
    bf16x8 pa1 = *(const bf16x8*)(ap + 32 + quad * 8);  /* cols>=36: finite x G-zeros */\
    f32x4 pg0 = {0,0,0,0}, pg1 = {0,0,0,0}, pg2 = {0,0,0,0};                            \
    {                                                                                   \
        bf16x8 t0 = *(const bf16x8*)&sG[(l15) * PG + quad * 8];                         \
        bf16x8 t1 = *(const bf16x8*)&sG[(l15) * PG + 32 + quad * 8];                    \
        bf16x8 t2 = *(const bf16x8*)&sG[(16 + l15) * PG + quad * 8];                    \
        bf16x8 t3 = *(const bf16x8*)&sG[(16 + l15) * PG + 32 + quad * 8];               \
        bf16x8 t4 = *(const bf16x8*)&sG[(rb2 + l15) * PG + quad * 8];                   \
        bf16x8 t5 = *(const bf16x8*)&sG[(rb2 + l15) * PG + 32 + quad * 8];              \
        __builtin_amdgcn_s_setprio(1);                                                  \
        pg0 = MFMA16(pa0, t0, pg0); pg0 = MFMA16(pa1, t1, pg0);                         \
        pg1 = MFMA16(pa0, t2, pg1); pg1 = MFMA16(pa1, t3, pg1);                         \
        pg2 = MFMA16(pa0, t4, pg2); pg2 = MFMA16(pa1, t5, pg2);                         \
        __builtin_amdgcn_s_setprio(0);                                                  \
    }                                                                                   \
    float4 wq = {0.f, 0.f, 0.f, 0.f};                                                   \
    if constexpr (USE_WS)                                                               \
        wq = *(const float4*)&w1g[(size_t)c * NW + (MT) * 16 + quad * 4];               \
    _Pragma("unroll")                                                                   \
    for (int p = 0; p < 4; ++p) {                                                       \
        float s2 = pg0[p] * acc[MT][0][p] + pg1[p] * acc[MT][1][p]                      \
                 + pg2[p] * acc[MT][2][p];                    /* acc holds e (f32) */   \
        s2 = dpp_add16(s2);                                                             \
        float w12 = dpp_add16(W12[p]);                                                  \
        float wf = USE_WS ? ((const float*)&wq)[p] : w1f[MT][p];                        \
        esum += exp2f(w12 * __frsqrt_rn(fmaxf(s2, 1e-16f)) * wf);                       \
    }                                                                                   \
} while (0)

// FINAL (R17 = R15 verbatim, the proven best: 113.8-114.8 us scan / 164.4 bench).
// Session ledger: 122.4 -> 113.5 us via W/R pipeline + in-place softmax (R8, +5.5%),
// setprio on MFMA clusters (R10, +2%), DPP esum join + v_log (R15, neutral-clean).
// Falsified >=2x each: occupancy levers (residency pinned ~3.2 blocks/CU by unified-reg
// footprint: R1/R5/R6), cross-caption ILP (R3/R9/R16 — ANY added live range >=4-12 regs
// across a stage boundary spills at this VGPR-60 operating point), phase restructuring
// (R4), reduction-pipe moves (R11-R15). Not a pipe roofline (MFMA 19%/VALU 48%/HBM 2.4%)
// — a structural latency floor of this decomposition. Spill canary: WRITE_SIZE ~135 KB.
template<bool USE_WS>
__global__ __attribute__((amdgpu_flat_work_group_size(256, 256), amdgpu_waves_per_eu(4, 8)))
void scan_main(const float* __restrict__ images,
               const float* __restrict__ captions,
               const bf16* __restrict__ capb,
               const float* __restrict__ w1g,
               float* __restrict__ out)
{
    __shared__ __align__(16) unsigned char smem[SMEM_TOTAL];
    bf16* sIb = (bf16*)(smem + OFF_IB);   // [r][d] image, 36 real rows only
    bf16* sG  = (bf16*)(smem + OFF_G);    // [r'][r] Gram, 36 rows x 72 cols (36..71 zero)

    const int tid  = threadIdx.x;
    const int wave = tid >> 6;
    const int lane = tid & 63;
    const int quad = lane >> 4;
    const int l15  = lane & 15;
    const int i    = blockIdx.x >> 4;
    const int c0   = (blockIdx.x & 15) * 16;  // chunk -> (chunk%8) XCD-affine captions

    bf16* bufA = (bf16*)(smem + OFF_P) + wave * (32 * PSP);   // two 16-row buffers
    bf16* bufB = bufA + 16 * PSP;

    const int rb2 = 20;   // r-tile bases {0,16,20}; tile 2 overlaps tile 1 on r=20..31

    // ---- init: stage image bf16, zero sG and sP+guard ----
    const float* gI = images + (size_t)i * NR * ND;
    #pragma unroll
    for (int k = 0; k < 9; ++k) {
        int t = tid + k * 256;               // 2304 float4
        int e = t * 4, r = e >> 8, d = e & 255;
        float4 v = *(const float4*)(gI + e);
        bf16x4 h = { (bf16)v.x, (bf16)v.y, (bf16)v.z, (bf16)v.w };
        *(bf16x4*)&sIb[r * PIB + d] = h;
    }
    {
        uint32_t* pG = (uint32_t*)sG;        // 1296 dwords
        #pragma unroll
        for (int k = 0; k < 6; ++k) { int x = tid + k * 256; if (x < 1296) pG[x] = 0u; }
        uint32_t* pP = (uint32_t*)(smem + OFF_P);   // sP buffers + guard: 3360 dwords
        #pragma unroll
        for (int k = 0; k < 14; ++k) { int x = tid + k * 256; if (x < 3360) pP[x] = 0u; }
        // cols 36..51 of each sP row are never written after this -> stay zero (k-pad safety)
    }
    __syncthreads();   // B0

    // ---- once: Gram G = I*I^T over overlapped m-tiles {0,16,20} (waves 0-2) ----
    if (wave < 3) {
        const int mb = (wave == 2) ? rb2 : wave * 16;
        f32x4 g0 = {0,0,0,0}, g1 = {0,0,0,0}, g2 = {0,0,0,0};
        #pragma unroll
        for (int ks = 0; ks < 8; ++ks) {
            bf16x8 a  = *(const bf16x8*)&sIb[(mb + l15)  * PIB + ks * 32 + quad * 8];
            bf16x8 b0 = *(const bf16x8*)&sIb[(l15)       * PIB + ks * 32 + quad * 8];
            bf16x8 b1 = *(const bf16x8*)&sIb[(16 + l15)  * PIB + ks * 32 + quad * 8];
            bf16x8 b2 = *(const bf16x8*)&sIb[(rb2 + l15) * PIB + ks * 32 + quad * 8];
            g0 = MFMA16(a, b0, g0); g1 = MFMA16(a, b1, g1); g2 = MFMA16(a, b2, g2);
        }
        // duplicate writes in overlap regions carry identical values (benign)
        #pragma unroll
        for (int p = 0; p < 4; ++p) {
            int m = mb + quad * 4 + p;
            sG[m * PG + l15]       = (bf16)g0[p];
            sG[m * PG + 16 + l15]  = (bf16)g1[p];
            sG[m * PG + rb2 + l15] = (bf16)g2[p];
        }
    }
    __syncthreads();   // B1: sG published. No further barriers.

    // ---- per-wave: 4 captions, everything in-wave ----
    for (int it = 0; it < 4; ++it) {
        const int c = c0 + wave * 4 + it;

        // ---- phase 1: raw logits attnT[w][r] = C_c . I^T ----
        f32x4 acc[3][3] = {};
        float ssc[3] = {0.f, 0.f, 0.f};
        float w1f[3][4] = {};                 // !USE_WS only (fallback path)
        const bf16*  ab   = USE_WS ? capb + ((size_t)c * NW + l15) * ND + quad * 8 : nullptr;
        const float* ab32 = USE_WS ? nullptr : captions + ((size_t)c * NW + l15) * ND + quad * 8;
        __builtin_amdgcn_s_setprio(1);        // MFMA-dense phase: bias CU scheduler
        #pragma unroll
        for (int ks = 0; ks < 8; ++ks) {
            bf16x8 a0, a1, a2;
            if (USE_WS) {
                a0 = *(const bf16x8*)(ab + ks * 32);
                a1 = *(const bf16x8*)(ab + 16 * ND + ks * 32);
                a2 = *(const bf16x8*)(ab + 32 * ND + ks * 32);
            } else {
                a0 = ld_cvt_f32(ab32 + ks * 32, ssc[0]);
                a1 = ld_cvt_f32(ab32 + 16 * ND + ks * 32, ssc[1]);
                a2 = ld_cvt_f32(ab32 + 32 * ND + ks * 32, ssc[2]);
            }
            bf16x8 b0 = *(const bf16x8*)&sIb[(l15)       * PIB + ks * 32 + quad * 8];
            bf16x8 b1 = *(const bf16x8*)&sIb[(16 + l15)  * PIB + ks * 32 + quad * 8];
            bf16x8 b2 = *(const bf16x8*)&sIb[(rb2 + l15) * PIB + ks * 32 + quad * 8];
            acc[0][0] = MFMA16(a0, b0, acc[0][0]);
            acc[1][0] = MFMA16(a1, b0, acc[1][0]);
            acc[2][0] = MFMA16(a2, b0, acc[2][0]);
            acc[0][1] = MFMA16(a0, b1, acc[0][1]);
            acc[1][1] = MFMA16(a1, b1, acc[1][1]);
            acc[2][1] = MFMA16(a2, b1, acc[2][1]);
            acc[0][2] = MFMA16(a0, b2, acc[0][2]);
            acc[1][2] = MFMA16(a1, b2, acc[1][2]);
            acc[2][2] = MFMA16(a2, b2, acc[2][2]);
        }
        __builtin_amdgcn_s_setprio(0);
        if (!USE_WS) {
            #pragma unroll
            for (int mt = 0; mt < 3; ++mt) {
                float s = ssc[mt];
                s += __shfl_xor(s, 16); s += __shfl_xor(s, 32);
                ssc[mt] = LSE_SCALE * __frsqrt_rn(fmaxf(s, 1e-16f));   // = LSE/w1
            }
            #pragma unroll
            for (int mt = 0; mt < 3; ++mt)
                #pragma unroll
                for (int p = 0; p < 4; ++p)
                    w1f[mt][p] = __shfl(ssc[mt], (lane & 48) + quad * 4 + p);
        }

        // ---- l2norm over w; nt=2 valid at l15>=12 (r=32..35) ----
        // fold 9*log2e*inv into the exp2 argument: exp2(c1*a + c2*|a|)
        float c1[3], c2[3];
        #pragma unroll
        for (int nt = 0; nt < 3; ++nt) {
            float s = 0.f;
            #pragma unroll
            for (int mt = 0; mt < 3; ++mt)
                #pragma unroll
                for (int p = 0; p < 4; ++p) { float t = lrelu(acc[mt][nt][p]); s += t * t; }
            s += __shfl_xor(s, 16); s += __shfl_xor(s, 32);       // sum over w-quads
            float inv = SOFT_SCALE * __frsqrt_rn(fmaxf(s, 1e-12f));
            c1[nt] = 0.55f * inv;
            c2[nt] = 0.45f * inv;
        }

        // ---- W/R pipeline over 2 buffers: every write->read RAW spans a full stage ----
        float esum = 0.f;
        float w12a[4], w12b[4], w12c[4];
        STAGE_W(0, bufA, w12a);
        STAGE_W(1, bufB, w12b);
        STAGE_R(0, bufA, w12a);       // bufA written 1 stage ago; W1's exps in the shadow
        STAGE_W(2, bufA, w12c);       // bufA free (R0's reads precede in-wave DS order)
        STAGE_R(1, bufB, w12b);
        STAGE_R(2, bufA, w12c);

        // final join on the VALU pipe (DPP); 64-lane sum = 16x the 4-row target
        // (per-lane esum identical within each row) -> exact 1/16 scale before log
        esum = wave_sum_row3(esum);
        if (lane == 63) out[(size_t)i * NC + c] = lse_out(esum * 0.0625f);
    }
}

extern "C" void kernel_launch(void* const* d_in, const int* in_sizes, int n_in,
                              void* d_out, int out_size, void* d_ws, size_t ws_size,
                              hipStream_t stream) {
    const float* images   = (const float*)d_in[0];   // (128, 36, 256) fp32
    const float* captions = (const float*)d_in[1];   // (256, 48, 256) fp32
    float* out = (float*)d_out;                      // (128, 256) fp32

    const size_t need_w1  = (size_t)NC * NW * sizeof(float);   // 49152
    const size_t need_cap = (size_t)NC * NW * ND * 2;          // 6291456
    bool use_ws = ws_size >= need_w1 + need_cap;

    dim3 grid(2048), block(256);   // R2/R8 launch geometry (proven best)
    if (use_ws) {
        float* w1g = (float*)d_ws;
        bf16*  capb = (bf16*)((char*)d_ws + need_w1);
        hipLaunchKernelGGL(prep_kernel, dim3(1024), dim3(256), 0, stream, captions, capb, w1g);
        hipLaunchKernelGGL((scan_main<true>), grid, block, 0, stream, images, captions, capb, w1g, out);
    } else {
        hipLaunchKernelGGL((scan_main<false>), grid, block, 0, stream, images, captions,
                           (const bf16*)nullptr, (const float*)nullptr, out);
    }
}